// Round 12
// baseline (247.727 us; speedup 1.0000x reference)
//
#include <hip/hip_runtime.h>

#define NUM_K 1024
#define DIM 256
#define HWDIM 1024
#define BETA 0.25f
#define NTOT 8388608  // 32*256*32*32
#define DIST_C 0.25f  // keeps dist = ||e||^2 + C - 2 x.e positive
#define ESCALE 512.0f // codebook stored as e*512 in fp8 e4m3
#define NEG2_OVER_ESCALE (-0.00390625f)  // -2/512

typedef __attribute__((ext_vector_type(4))) float fx4;
typedef unsigned int u32;

// ws floats: [0] loss acc | [64..1088) enorm+C | [1088..66624) fp8 frag cb (256 KB)
//   | [66624..99392) keys u32[32768] | [99392..99648) tile counters u32[256]
//   | [99648] done counter
// cb frag layout: [gc=code/16][s=0..7][lane=0..63][8B]; code = gc*16+(lane&15),
// dim = s*32+(lane>>4)*8+e.  Slice sc = 32 KB contiguous at sc*32768.
#define WS_CB 1088
#define WS_KEYS 66624
#define WS_TCNT 99392
#define WS_DCNT 99648

// prep: [0,128) fp8 frag cb | [128,384) enorm+C | [384,512) keys + counters init
__global__ void prep_kernel(const float* __restrict__ wgt, float* __restrict__ ws) {
    if (blockIdx.x < 128) {
        int g = blockIdx.x * 256 + threadIdx.x;       // 0..32767, 8 bytes each
        int lane = g & 63, s = (g >> 6) & 7, gc = g >> 9;
        int code = gc * 16 + (lane & 15);
        int d0 = s * 32 + (lane >> 4) * 8;
        const float* p = wgt + (size_t)code * DIM + d0;
        float4 a = *reinterpret_cast<const float4*>(p);
        float4 b = *reinterpret_cast<const float4*>(p + 4);
        u32 w0 = 0, w1 = 0;
        w0 = __builtin_amdgcn_cvt_pk_fp8_f32(a.x * ESCALE, a.y * ESCALE, w0, false);
        w0 = __builtin_amdgcn_cvt_pk_fp8_f32(a.z * ESCALE, a.w * ESCALE, w0, true);
        w1 = __builtin_amdgcn_cvt_pk_fp8_f32(b.x * ESCALE, b.y * ESCALE, w1, false);
        w1 = __builtin_amdgcn_cvt_pk_fp8_f32(b.z * ESCALE, b.w * ESCALE, w1, true);
        u32* dst = reinterpret_cast<u32*>(ws + WS_CB) + (size_t)g * 2;
        dst[0] = w0; dst[1] = w1;
    } else if (blockIdx.x < 384) {
        int wave = threadIdx.x >> 6, lane = threadIdx.x & 63;
        int k = (blockIdx.x - 128) * 4 + wave;
        const float4 v = *reinterpret_cast<const float4*>(wgt + (size_t)k * DIM + lane * 4);
        float s = v.x * v.x + v.y * v.y + v.z * v.z + v.w * v.w;
        #pragma unroll
        for (int off = 32; off > 0; off >>= 1) s += __shfl_down(s, off, 64);
        if (lane == 0) ws[64 + k] = s + DIST_C;
    } else {
        u32* keys = reinterpret_cast<u32*>(ws + WS_KEYS);
        keys[(blockIdx.x - 384) * 256 + threadIdx.x] = 0xFFFFFFFFu;
        if (blockIdx.x == 384) {
            reinterpret_cast<u32*>(ws + WS_TCNT)[threadIdx.x] = 0u;
            if (threadIdx.x == 0) {
                reinterpret_cast<u32*>(ws + WS_DCNT)[0] = 0u;
                ws[0] = 0.f;
            }
        }
    }
}

__device__ __forceinline__ void gl2lds16(const void* g, void* l) {
    __builtin_amdgcn_global_load_lds(
        (const __attribute__((address_space(1))) u32*)g,
        (__attribute__((address_space(3))) u32*)l, 16, 0, 0);
}

__launch_bounds__(256, 2)
__global__ void vq_kernel(const float* __restrict__ in,
                          const float* __restrict__ wgt,
                          float* __restrict__ ws,
                          float* __restrict__ out) {
    // LDS: [0,32K) xs fp8 x-tile frag-ordered (lane-slot XOR-swizzled);
    //      [32K,64K) cb slice; [64K,+512) eno.  idxs aliases xs in scatter phase.
    __shared__ __align__(16) unsigned char smem[66048];
    __shared__ u32 scf;
    unsigned char* xs = smem;
    unsigned char* cbl = smem + 32768;
    float* eno = reinterpret_cast<float*>(smem + 65536);

    const int tid = threadIdx.x;
    const int lane = tid & 63;
    const int wv = tid >> 6;         // 4 waves
    const int wr = wv >> 1;          // row half:  rows [wr*64, +64)
    const int wc = wv & 1;           // code half: slice-codes [wc*64, +64)
    const int tx = lane & 15;
    const int tz = lane >> 4;

    // XCD-swizzle: all 8 slice-blocks of a tile land on one XCD, back-to-back
    const int bid = blockIdx.x;
    const int t  = (bid & 7) * 32 + (bid >> 6);   // row-tile 0..255 (128 rows)
    const int sc = (bid >> 3) & 7;                // code-slice 0..7 (128 codes)
    const int bb = t >> 3;
    const int hw0 = (t & 7) << 7;
    const float* inb = in + (size_t)bb * (DIM * HWDIM) + hw0;

    // ---- burst-stage cb slice (8 gl2lds/thread, all in flight) ----
    const unsigned char* cbg = reinterpret_cast<const unsigned char*>(ws + WS_CB)
                               + (size_t)sc * 32768;
    #pragma unroll
    for (int i = 0; i < 8; ++i)
        gl2lds16(cbg + i * 4096 + tid * 16, cbl + i * 4096 + tid * 16);

    // ---- eno slice ----
    if (tid < 128) eno[tid] = ws[64 + sc * 128 + tid];

    // ---- stage x: fp32 [d][hw] -> fp8 frag-ordered LDS (lane-slot XOR); xsq ----
    float xsq = 0.f;
    {
        const int hw4 = (tid & 31) << 2;      // 4 local rows
        const int dq = tid >> 5;              // 0..7
        #pragma unroll
        for (int it = 0; it < 8; ++it) {
            int d0 = dq * 4 + it * 32;
            float4 r0 = *reinterpret_cast<const float4*>(inb + (size_t)(d0 + 0) * HWDIM + hw4);
            float4 r1 = *reinterpret_cast<const float4*>(inb + (size_t)(d0 + 1) * HWDIM + hw4);
            float4 r2 = *reinterpret_cast<const float4*>(inb + (size_t)(d0 + 2) * HWDIM + hw4);
            float4 r3 = *reinterpret_cast<const float4*>(inb + (size_t)(d0 + 3) * HWDIM + hw4);
            xsq += r0.x * r0.x + r0.y * r0.y + r0.z * r0.z + r0.w * r0.w
                 + r1.x * r1.x + r1.y * r1.y + r1.z * r1.z + r1.w * r1.w
                 + r2.x * r2.x + r2.y * r2.y + r2.z * r2.z + r2.w * r2.w
                 + r3.x * r3.x + r3.y * r3.y + r3.z * r3.z + r3.w * r3.w;
            float q0[4] = {r0.x, r0.y, r0.z, r0.w};
            float q1[4] = {r1.x, r1.y, r1.z, r1.w};
            float q2[4] = {r2.x, r2.y, r2.z, r2.w};
            float q3[4] = {r3.x, r3.y, r3.z, r3.w};
            #pragma unroll
            for (int jj = 0; jj < 4; ++jj) {
                int lr = hw4 + jj;            // local row 0..127
                u32 w = 0;
                w = __builtin_amdgcn_cvt_pk_fp8_f32(q0[jj], q1[jj], w, false);
                w = __builtin_amdgcn_cvt_pk_fp8_f32(q2[jj], q3[jj], w, true);
                int rg = lr >> 4;
                // lane-slot XOR swizzle: spreads banks, bijective per (rg,s)
                int lslot = ((lr & 15) ^ (rg & 7)) | ((dq >> 1) << 4);
                *reinterpret_cast<u32*>(xs + rg * 4096 + it * 512
                                        + lslot * 8 + ((dq & 1) << 2)) = w;
            }
        }
    }

    asm volatile("s_waitcnt vmcnt(0)" ::: "memory");
    __syncthreads();   // xs + cbl + eno ready; never rewritten before scatter phase

    // ---- hoist A fragments: rows (wr*4+rf)*16 + tx, lane-slot un-swizzled ----
    long af[4][8];
    #pragma unroll
    for (int rf = 0; rf < 4; ++rf) {
        const int rg = wr * 4 + rf;
        const int lslot = ((lane & 15) ^ (rg & 7)) | ((lane >> 4) << 4);
        #pragma unroll
        for (int s = 0; s < 8; ++s)
            af[rf][s] = *reinterpret_cast<const long*>(
                xs + rg * 4096 + s * 512 + lslot * 8);
    }

    float minkey[16];
    #pragma unroll
    for (int q = 0; q < 16; ++q) minkey[q] = 1e30f;

    // ---- compute: 4 code-groups x (8 ds_read_b64 + 32 MFMA + argmin), all LDS ----
    #pragma unroll
    for (int cg = 0; cg < 4; ++cg) {
        const int gi = wc * 4 + cg;
        const unsigned char* cbp = cbl + gi * 4096 + lane * 8;
        long bf[8];
        #pragma unroll
        for (int s = 0; s < 8; ++s)
            bf[s] = *reinterpret_cast<const long*>(cbp + s * 512);
        fx4 acc[4];
        const fx4 z = {0.f, 0.f, 0.f, 0.f};
        #pragma unroll
        for (int rf = 0; rf < 4; ++rf) acc[rf] = z;
        __builtin_amdgcn_s_setprio(1);
        #pragma unroll
        for (int s = 0; s < 8; ++s) {
            #pragma unroll
            for (int rf = 0; rf < 4; ++rf)
                acc[rf] = __builtin_amdgcn_mfma_f32_16x16x32_fp8_fp8(af[rf][s], bf[s], acc[rf], 0, 0, 0);
        }
        __builtin_amdgcn_s_setprio(0);
        const int codebase = sc * 128 + gi * 16 + tx;
        const float en = eno[gi * 16 + tx];
        #pragma unroll
        for (int rf = 0; rf < 4; ++rf) {
            #pragma unroll
            for (int r = 0; r < 4; ++r) {
                float d = fmaf(NEG2_OVER_ESCALE, acc[rf][r], en);
                u32 u = (__builtin_bit_cast(u32, d) & 0xFFFFFC00u) | (u32)codebase;
                minkey[rf * 4 + r] = fminf(minkey[rf * 4 + r], __builtin_bit_cast(float, u));
            }
        }
    }

    // ---- xsq: once per tile (sc==0 blocks) ----
    #pragma unroll
    for (int off = 32; off > 0; off >>= 1) xsq += __shfl_down(xsq, off, 64);
    if (sc == 0 && lane == 0) atomicAdd(&ws[0], xsq);

    // ---- reduce over the 16 col-lanes ----
    #pragma unroll
    for (int q = 0; q < 16; ++q) {
        float v = minkey[q];
        #pragma unroll
        for (int off = 1; off < 16; off <<= 1)
            v = fminf(v, __shfl_xor(v, off, 64));
        minkey[q] = v;
    }

    // ---- global argmin combine: atomicMin on bit-packed keys ----
    u32* keysp = reinterpret_cast<u32*>(ws + WS_KEYS) + t * 128;
    if (tx == 0) {
        #pragma unroll
        for (int rf = 0; rf < 4; ++rf) {
            #pragma unroll
            for (int r = 0; r < 4; ++r)
                atomicMin(&keysp[wr * 64 + rf * 16 + tz * 4 + r],
                          __builtin_bit_cast(u32, minkey[rf * 4 + r]));
        }
    }

    // ---- per-tile ticket: 8th arriver scatters this tile ----
    __threadfence();
    __syncthreads();
    if (tid == 0)
        scf = (atomicAdd(&reinterpret_cast<u32*>(ws + WS_TCNT)[t], 1u) == 7u) ? 1u : 0u;
    __syncthreads();
    if (scf) {
        int* idxs = reinterpret_cast<int*>(smem);   // xs dead now
        float dsel = 0.f;
        if (tid < 128) {
            u32 kk = atomicMin(&keysp[tid], 0xFFFFFFFFu);   // device-scope read
            idxs[tid] = (int)(kk & 0x3FFu);
            dsel = __builtin_bit_cast(float, kk & 0xFFFFFC00u) - DIST_C;
        }
        #pragma unroll
        for (int off = 32; off > 0; off >>= 1) dsel += __shfl_down(dsel, off, 64);
        if (tid < 128 && (tid & 63) == 0) atomicAdd(&ws[0], dsel);
        __syncthreads();
        {
            const int hw4s = (tid & 31) << 2;
            const int dq8 = tid >> 5;            // 0..7, 32 dims each
            int k0 = idxs[hw4s + 0], k1 = idxs[hw4s + 1];
            int k2 = idxs[hw4s + 2], k3 = idxs[hw4s + 3];
            const float* e0 = wgt + (size_t)k0 * DIM;
            const float* e1 = wgt + (size_t)k1 * DIM;
            const float* e2 = wgt + (size_t)k2 * DIM;
            const float* e3 = wgt + (size_t)k3 * DIM;
            float* outb = out + (size_t)bb * (DIM * HWDIM) + hw0;
            #pragma unroll
            for (int m = 0; m < 8; ++m) {
                int d0 = dq8 * 32 + m * 4;
                float4 r0v = *reinterpret_cast<const float4*>(e0 + d0);
                float4 r1v = *reinterpret_cast<const float4*>(e1 + d0);
                float4 r2v = *reinterpret_cast<const float4*>(e2 + d0);
                float4 r3v = *reinterpret_cast<const float4*>(e3 + d0);
                float er0[4] = {r0v.x, r0v.y, r0v.z, r0v.w};
                float er1[4] = {r1v.x, r1v.y, r1v.z, r1v.w};
                float er2[4] = {r2v.x, r2v.y, r2v.z, r2v.w};
                float er3[4] = {r3v.x, r3v.y, r3v.z, r3v.w};
                #pragma unroll
                for (int qd = 0; qd < 4; ++qd) {
                    float4 ev = {er0[qd], er1[qd], er2[qd], er3[qd]};
                    *reinterpret_cast<float4*>(outb + (size_t)(d0 + qd) * HWDIM + hw4s) = ev;
                }
            }
        }
        // ---- global ticket: 256th scatterer finalizes the loss ----
        __threadfence();
        __syncthreads();
        if (tid == 0) {
            u32 od = atomicAdd(reinterpret_cast<u32*>(ws + WS_DCNT), 1u);
            if (od == 255u) {
                float tot = atomicAdd(&ws[0], 0.0f);    // device-scope read
                out[NTOT] = (1.f + BETA) * tot / (float)NTOT;
            }
        }
    }
}

extern "C" void kernel_launch(void* const* d_in, const int* in_sizes, int n_in,
                              void* d_out, int out_size, void* d_ws, size_t ws_size,
                              hipStream_t stream) {
    const float* enc = (const float*)d_in[0];
    const float* wgt = (const float*)d_in[1];
    float* out = (float*)d_out;
    float* ws = (float*)d_ws;

    prep_kernel<<<512, 256, 0, stream>>>(wgt, ws);
    vq_kernel<<<2048, 256, 0, stream>>>(enc, wgt, ws, out);
}